// Round 3
// baseline (206.791 us; speedup 1.0000x reference)
//
#include <hip/hip_runtime.h>
#include <math.h>

static constexpr int Bq  = 8;
static constexpr int DIN = 1024;
static constexpr int TTT = 2048;
static constexpr int KCB = 8192;

static constexpr int NCH = 64;    // VQ chunks
static constexpr int CPC = 128;   // codes per chunk (NCH*CPC == KCB)

// d_out layout (floats)
static constexpr size_t OUT_OFS  = 0;
static constexpr size_t LOSS_OFS = (size_t)Bq * DIN * TTT;      // 16777216 (16 zeros)
static constexpr size_t IDX_OFS  = LOSS_OFS + 16;               // 16777232 (B*T)
static constexpr size_t ZE_OFS   = IDX_OFS + (size_t)Bq * TTT;  // 16793616 (B*8*T)

// ws layout (float offsets)
static constexpr size_t WS_CBN  = 0;          // 8192*8 normalized codebook
static constexpr size_t WS_C2   = 65536;      // 8192 0.5*||c_n||^2
static constexpr size_t WS_WT   = 73728;      // 1024*8 transposed w_in
static constexpr size_t WS_ENC  = 81920;      // 16384*8 z_e rows; k1b: -normalized
static constexpr size_t WS_Q    = 212992;     // 16384*8 gathered codebook rows
static constexpr size_t WS_PART = 344064;     // float2[NCH][16384] (score, idxbits)
static constexpr size_t WS_IDXI = WS_PART + (size_t)2 * NCH * 16384; // 16384 ints

// ---------------- K0: normalize codebook, transpose w_in, zero losses ----------
__global__ __launch_bounds__(256) void k0_prep(
    const float* __restrict__ w_in, const float* __restrict__ codebook,
    float* __restrict__ ws, float* __restrict__ out)
{
  int tid = blockIdx.x * 256 + threadIdx.x;
  if (tid < KCB) {
    const float4* cp = (const float4*)(codebook + (size_t)tid * 8);
    float4 a = cp[0], b = cp[1];
    float v[8] = {a.x, a.y, a.z, a.w, b.x, b.y, b.z, b.w};
    float n2 = 0.f;
#pragma unroll
    for (int o = 0; o < 8; o++) n2 = fmaf(v[o], v[o], n2);
    float dn = fmaxf(sqrtf(n2), 1e-12f);
    float u[8];
    float s2 = 0.f;
#pragma unroll
    for (int o = 0; o < 8; o++) { u[o] = v[o] / dn; s2 = fmaf(u[o], u[o], s2); }
    float4* wp = (float4*)(ws + WS_CBN + (size_t)tid * 8);
    wp[0] = make_float4(u[0], u[1], u[2], u[3]);
    wp[1] = make_float4(u[4], u[5], u[6], u[7]);
    ws[WS_C2 + tid] = 0.5f * s2;  // score = 0.5*||c||^2 - dot (monotone per row)
  } else if (tid < KCB + DIN) {
    int d = tid - KCB;
#pragma unroll
    for (int o = 0; o < 8; o++) ws[WS_WT + (size_t)d * 8 + o] = w_in[(size_t)o * DIN + d];
  } else if (tid < KCB + DIN + 16) {
    out[LOSS_OFS + (tid - KCB - DIN)] = 0.f;  // commit_loss + codebook_loss zeros
  }
}

// ---------------- K1: z_e = w_in @ z + b_in  (HBM-bound, 64 MiB read) ----------
// grid 1024 = b(8) x t-tiles(128 of 16 t). block 256: dg=tid>>2 (64 d-groups,
// d = dg + 64*i interleaved), tt=tid&3 (4 t's via float4). w read from L1/L2
// (no LDS staging -> no bank conflicts). Padded-stride LDS partial reduce.
__global__ __launch_bounds__(256, 4) void k1_proj_in(
    const float* __restrict__ z, const float* __restrict__ b_in,
    float* __restrict__ ws, float* __restrict__ out)
{
  __shared__ __align__(16) float lds[64 * 136];  // 34.8 KB padded partials
  int tid = threadIdx.x;
  int bx = blockIdx.x;
  int b = bx >> 7;
  int t0 = (bx & 127) << 4;
  int dg = tid >> 2;
  int tt = tid & 3;
  const float* zb = z + (size_t)b * DIN * TTT + t0 + (tt << 2);
  const float4* wt = (const float4*)(ws + WS_WT);
  float4 acc[8];
#pragma unroll
  for (int o = 0; o < 8; o++) acc[o] = make_float4(0.f, 0.f, 0.f, 0.f);
#pragma unroll 4
  for (int i = 0; i < 16; i++) {
    int d = dg + (i << 6);
    float4 zv = *(const float4*)(zb + (size_t)d * TTT);
    float4 w0 = wt[d * 2 + 0];
    float4 w1 = wt[d * 2 + 1];
#define ACC1(o, wsc)                                    \
    acc[o].x = fmaf(wsc, zv.x, acc[o].x);               \
    acc[o].y = fmaf(wsc, zv.y, acc[o].y);               \
    acc[o].z = fmaf(wsc, zv.z, acc[o].z);               \
    acc[o].w = fmaf(wsc, zv.w, acc[o].w);
    ACC1(0, w0.x) ACC1(1, w0.y) ACC1(2, w0.z) ACC1(3, w0.w)
    ACC1(4, w1.x) ACC1(5, w1.y) ACC1(6, w1.z) ACC1(7, w1.w)
#undef ACC1
  }
  {
    float* pl = lds + dg * 136 + (tt << 2);
#pragma unroll
    for (int o = 0; o < 8; o++) *(float4*)(pl + o * 16) = acc[o];
  }
  __syncthreads();
  if (tid < 128) {
    int o = tid >> 4;
    int t = tid & 15;
    float s = 0.f;
#pragma unroll
    for (int g = 0; g < 64; g++) s += lds[g * 136 + (o << 4) + t];
    s += b_in[o];
    out[ZE_OFS + ((size_t)b * 8 + o) * TTT + t0 + t] = s;
    ws[WS_ENC + ((size_t)b * TTT + t0 + t) * 8 + o] = s;
  }
}

// ---------------- K1b: normalize+negate enc rows in place (once per row) -------
__global__ __launch_bounds__(256) void k1b_norm(float* __restrict__ ws)
{
  int r = blockIdx.x * 256 + threadIdx.x;
  float4* ep = (float4*)(ws + WS_ENC + (size_t)r * 8);
  float4 a = ep[0], c = ep[1];
  float n2 = 0.f;
  n2 = fmaf(a.x, a.x, n2); n2 = fmaf(a.y, a.y, n2);
  n2 = fmaf(a.z, a.z, n2); n2 = fmaf(a.w, a.w, n2);
  n2 = fmaf(c.x, c.x, n2); n2 = fmaf(c.y, c.y, n2);
  n2 = fmaf(c.z, c.z, n2); n2 = fmaf(c.w, c.w, n2);
  float dn = fmaxf(sqrtf(n2), 1e-12f);
  a.x = -(a.x / dn); a.y = -(a.y / dn); a.z = -(a.z / dn); a.w = -(a.w / dn);
  c.x = -(c.x / dn); c.y = -(c.y / dn); c.z = -(c.z / dn); c.w = -(c.w / dn);
  ep[0] = a; ep[1] = c;
}

// ---------------- K2: VQ scan. grid 1024 = rowblocks(16) x chunks(64)
// block 256, R=4 rows/thread (pre-negated-normalized, ~55 VGPR -> resident),
// CPC=128 codes staged in LDS. score = 0.5*||c||^2 - enc_n.c
__global__ __launch_bounds__(256, 4) void k2_scan(float* __restrict__ ws)
{
  __shared__ __align__(16) float4 scb[CPC * 2];
  __shared__ float sch[CPC];
  int tid = threadIdx.x;
  int rb = blockIdx.x >> 6;  // 16 rowblocks of 1024 rows
  int ch = blockIdx.x & 63;  // 64 chunks
  int k0 = ch << 7;          // CPC codes per chunk
  if (tid < CPC) {
    const float4* src = (const float4*)(ws + WS_CBN + (size_t)(k0 + tid) * 8);
    scb[tid * 2]     = src[0];
    scb[tid * 2 + 1] = src[1];
    sch[tid] = ws[WS_C2 + k0 + tid];
  }
  int rbase = (rb << 10) + tid;  // rows rbase + j*256, j<4

#define DECL_ROW(j) float4 m##j##a, m##j##b; float b##j = 3.4e38f; int i##j = 0;
  DECL_ROW(0) DECL_ROW(1) DECL_ROW(2) DECL_ROW(3)
#undef DECL_ROW
#define LOAD_ROW(j) {                                                         \
    const float4* ep = (const float4*)(ws + WS_ENC + (size_t)(rbase + (j << 8)) * 8); \
    m##j##a = ep[0]; m##j##b = ep[1]; }
  LOAD_ROW(0) LOAD_ROW(1) LOAD_ROW(2) LOAD_ROW(3)
#undef LOAD_ROW

  __syncthreads();
#pragma unroll 4
  for (int k = 0; k < CPC; k++) {
    float4 c0 = scb[2 * k];
    float4 c1 = scb[2 * k + 1];
    float cc = sch[k];
    int kk = k0 + k;
#define STEP(j) {                                                             \
    float s = cc;                                                             \
    s = fmaf(m##j##a.x, c0.x, s); s = fmaf(m##j##a.y, c0.y, s);               \
    s = fmaf(m##j##a.z, c0.z, s); s = fmaf(m##j##a.w, c0.w, s);               \
    s = fmaf(m##j##b.x, c1.x, s); s = fmaf(m##j##b.y, c1.y, s);               \
    s = fmaf(m##j##b.z, c1.z, s); s = fmaf(m##j##b.w, c1.w, s);               \
    if (s < b##j) { b##j = s; i##j = kk; } }
    STEP(0) STEP(1) STEP(2) STEP(3)
#undef STEP
  }
  float2* part = (float2*)(ws + WS_PART);
#define STORE_ROW(j) \
  part[(size_t)ch * 16384 + rbase + (j << 8)] = make_float2(b##j, __int_as_float(i##j));
  STORE_ROW(0) STORE_ROW(1) STORE_ROW(2) STORE_ROW(3)
#undef STORE_ROW
}

// ---------------- K2b: reduce chunk partials + gather codebook row -> WS_Q ----
__global__ __launch_bounds__(256) void k2b_reduce(
    const float* __restrict__ codebook, float* __restrict__ ws, float* __restrict__ out)
{
  int r = blockIdx.x * 256 + threadIdx.x;
  const float2* part = (const float2*)(ws + WS_PART);
  float best = 3.4e38f;
  int bi = 0;
#pragma unroll 8
  for (int ch = 0; ch < NCH; ch++) {
    float2 p = part[(size_t)ch * 16384 + r];
    if (p.x < best) { best = p.x; bi = __float_as_int(p.y); }  // ascending => first min
  }
  out[IDX_OFS + r] = (float)bi;
  ((int*)(ws + WS_IDXI))[r] = bi;
  const float4* cb = (const float4*)codebook;
  float4* q = (float4*)(ws + WS_Q + (size_t)r * 8);
  q[0] = cb[(size_t)bi * 2];
  q[1] = cb[(size_t)bi * 2 + 1];
}

// ---------------- K3: out = w_out @ q + b_out (HBM write-bound, no gathers) ----
__global__ __launch_bounds__(256) void k3_proj_out(
    const float* __restrict__ w_out, const float* __restrict__ b_out,
    const float* __restrict__ ws, float* __restrict__ out)
{
  int bx = blockIdx.x;
  int b = bx >> 7;
  int th = (bx >> 6) & 1;
  int dt = bx & 63;
  int tid = threadIdx.x;
  int t = (th << 10) + (tid << 2);
  const float4* qp = (const float4*)(ws + WS_Q + ((size_t)b * TTT + t) * 8);
  float4 c00 = qp[0], c01 = qp[1];
  float4 c10 = qp[2], c11 = qp[3];
  float4 c20 = qp[4], c21 = qp[5];
  float4 c30 = qp[6], c31 = qp[7];
  int d0 = dt << 4;
#pragma unroll 4
  for (int dd = 0; dd < 16; dd++) {
    int d = d0 + dd;
    const float* wr = w_out + (size_t)d * 8;
    float w0 = wr[0], w1 = wr[1], w2 = wr[2], w3 = wr[3];
    float w4 = wr[4], w5 = wr[5], w6 = wr[6], w7 = wr[7];
    float bb = b_out[d];
#define DOT8(lo, hi)                                                          \
    fmaf(w7, hi.w, fmaf(w6, hi.z, fmaf(w5, hi.y, fmaf(w4, hi.x,              \
    fmaf(w3, lo.w, fmaf(w2, lo.z, fmaf(w1, lo.y, fmaf(w0, lo.x, bb))))))))
    float4 r;
    r.x = DOT8(c00, c01);
    r.y = DOT8(c10, c11);
    r.z = DOT8(c20, c21);
    r.w = DOT8(c30, c31);
#undef DOT8
    *(float4*)(out + OUT_OFS + ((size_t)b * DIN + d) * TTT + t) = r;
  }
}

extern "C" void kernel_launch(void* const* d_in, const int* in_sizes, int n_in,
                              void* d_out, int out_size, void* d_ws, size_t ws_size,
                              hipStream_t stream) {
  const float* z        = (const float*)d_in[0];
  const float* w_in     = (const float*)d_in[1];
  const float* b_in     = (const float*)d_in[2];
  const float* w_out    = (const float*)d_in[3];
  const float* b_out    = (const float*)d_in[4];
  const float* codebook = (const float*)d_in[5];
  float* out = (float*)d_out;
  float* ws  = (float*)d_ws;

  k0_prep<<<dim3(37), dim3(256), 0, stream>>>(w_in, codebook, ws, out);
  k1_proj_in<<<dim3(1024), dim3(256), 0, stream>>>(z, b_in, ws, out);
  k1b_norm<<<dim3(64), dim3(256), 0, stream>>>(ws);
  k2_scan<<<dim3(1024), dim3(256), 0, stream>>>(ws);
  k2b_reduce<<<dim3(64), dim3(256), 0, stream>>>(codebook, ws, out);
  k3_proj_out<<<dim3(1024), dim3(256), 0, stream>>>(w_out, b_out, ws, out);
}

// Round 4
// 196.350 us; speedup vs baseline: 1.0532x; 1.0532x over previous
//
#include <hip/hip_runtime.h>
#include <math.h>

static constexpr int Bq  = 8;
static constexpr int DIN = 1024;
static constexpr int TTT = 2048;
static constexpr int KCB = 8192;

static constexpr int NCH = 64;    // VQ chunks
static constexpr int CPC = 128;   // codes per chunk (NCH*CPC == KCB)

// d_out layout (floats)
static constexpr size_t OUT_OFS  = 0;
static constexpr size_t LOSS_OFS = (size_t)Bq * DIN * TTT;      // 16777216 (16 zeros)
static constexpr size_t IDX_OFS  = LOSS_OFS + 16;               // 16777232 (B*T)
static constexpr size_t ZE_OFS   = IDX_OFS + (size_t)Bq * TTT;  // 16793616 (B*8*T)

// ws layout (float offsets)
static constexpr size_t WS_CBN  = 0;          // 8192*8 normalized codebook
static constexpr size_t WS_C2   = 65536;      // 8192 0.5*||c_n||^2
static constexpr size_t WS_WT   = 73728;      // 1024*8 transposed w_in
static constexpr size_t WS_ENC  = 81920;      // 16384*8 negated-normalized enc rows
static constexpr size_t WS_Q    = 212992;     // 16384*8 gathered codebook rows
static constexpr size_t WS_PART = 344064;     // float2[NCH][16384] (score, idxbits)
static constexpr size_t WS_IDXI = WS_PART + (size_t)2 * NCH * 16384; // 16384 ints

// ---------------- K0: normalize codebook, transpose w_in, zero losses ----------
__global__ __launch_bounds__(256) void k0_prep(
    const float* __restrict__ w_in, const float* __restrict__ codebook,
    float* __restrict__ ws, float* __restrict__ out)
{
  int tid = blockIdx.x * 256 + threadIdx.x;
  if (tid < KCB) {
    const float4* cp = (const float4*)(codebook + (size_t)tid * 8);
    float4 a = cp[0], b = cp[1];
    float v[8] = {a.x, a.y, a.z, a.w, b.x, b.y, b.z, b.w};
    float n2 = 0.f;
#pragma unroll
    for (int o = 0; o < 8; o++) n2 = fmaf(v[o], v[o], n2);
    float dn = fmaxf(sqrtf(n2), 1e-12f);
    float u[8];
    float s2 = 0.f;
#pragma unroll
    for (int o = 0; o < 8; o++) { u[o] = v[o] / dn; s2 = fmaf(u[o], u[o], s2); }
    float4* wp = (float4*)(ws + WS_CBN + (size_t)tid * 8);
    wp[0] = make_float4(u[0], u[1], u[2], u[3]);
    wp[1] = make_float4(u[4], u[5], u[6], u[7]);
    ws[WS_C2 + tid] = 0.5f * s2;  // score = 0.5*||c||^2 - dot (monotone per row)
  } else if (tid < KCB + DIN) {
    int d = tid - KCB;
#pragma unroll
    for (int o = 0; o < 8; o++) ws[WS_WT + (size_t)d * 8 + o] = w_in[(size_t)o * DIN + d];
  } else if (tid < KCB + DIN + 16) {
    out[LOSS_OFS + (tid - KCB - DIN)] = 0.f;  // commit_loss + codebook_loss zeros
  }
}

// ---------------- K1: z_e = w_in@z + b_in, + in-kernel normalize (fused k1b) ---
// grid 512 = b(8) x t-tiles(64 of 32 t). block 256: dg=tid>>3 (32 d-groups,
// d = dg + 32*i), tt=tid&7 (8 t-quads -> 32 t = one full 128B line per row).
// Padded LDS partial reduce (stride 264: 2-way max = free), then per-row
// normalization in a small LDS buffer. Writes z_e (out) + negated-normalized
// rows (WS_ENC).
__global__ __launch_bounds__(256, 2) void k1_proj_in(
    const float* __restrict__ z, const float* __restrict__ b_in,
    const float* __restrict__ wt, float* __restrict__ enc, float* __restrict__ out)
{
  __shared__ __align__(16) float lds[32 * 264 + 8 * 33];  // 34.9 KB
  int tid = threadIdx.x;
  int b = blockIdx.x >> 6;
  int t0 = (blockIdx.x & 63) << 5;
  int dg = tid >> 3;
  int tt = tid & 7;
  const float* zb = z + (size_t)b * DIN * TTT + t0 + (tt << 2);
  const float4* wtp = (const float4*)wt;
  float4 acc[8];
#pragma unroll
  for (int o = 0; o < 8; o++) acc[o] = make_float4(0.f, 0.f, 0.f, 0.f);
#pragma unroll 4
  for (int i = 0; i < 32; i++) {
    int d = dg + (i << 5);
    float4 zv = *(const float4*)(zb + (size_t)d * TTT);
    float4 w0 = wtp[d * 2 + 0];
    float4 w1 = wtp[d * 2 + 1];
#define ACC1(o, wsc)                                    \
    acc[o].x = fmaf(wsc, zv.x, acc[o].x);               \
    acc[o].y = fmaf(wsc, zv.y, acc[o].y);               \
    acc[o].z = fmaf(wsc, zv.z, acc[o].z);               \
    acc[o].w = fmaf(wsc, zv.w, acc[o].w);
    ACC1(0, w0.x) ACC1(1, w0.y) ACC1(2, w0.z) ACC1(3, w0.w)
    ACC1(4, w1.x) ACC1(5, w1.y) ACC1(6, w1.z) ACC1(7, w1.w)
#undef ACC1
  }
  {
    float* pl = lds + dg * 264 + (tt << 2);
#pragma unroll
    for (int o = 0; o < 8; o++) *(float4*)(pl + (o << 5)) = acc[o];
  }
  __syncthreads();
  int o = tid >> 5;          // 8 output channels
  int t = tid & 31;          // 32 t's
  float s = 0.f;
#pragma unroll
  for (int g = 0; g < 32; g++) s += lds[g * 264 + (o << 5) + t];
  s += b_in[o];
  out[ZE_OFS + ((size_t)b * 8 + o) * TTT + t0 + t] = s;
  float* nb = lds + 32 * 264;
  nb[o * 33 + t] = s;
  __syncthreads();
  float n2 = 0.f;
#pragma unroll
  for (int j = 0; j < 8; j++) { float v = nb[j * 33 + t]; n2 = fmaf(v, v, n2); }
  float dn = fmaxf(sqrtf(n2), 1e-12f);
  enc[((size_t)b * TTT + t0 + t) * 8 + o] = -(s / dn);
}

// ---------------- K2: VQ scan. grid 1024 = rowblocks(16) x chunks(64)
// block 256, R=4 rows/thread in VGPRs; codes read via wave-uniform scalar
// loads (s_load -> SGPR, one SGPR operand per v_fma is free). NO LDS in the
// inner loop. score = 0.5*||c||^2 - enc_n.c  (monotone transform per row).
__global__ __launch_bounds__(256, 4) void k2_scan(
    const float* __restrict__ cbn, const float* __restrict__ c2h,
    const float* __restrict__ enc, float2* __restrict__ part)
{
  int tid = threadIdx.x;
  int rb = blockIdx.x >> 6;  // 16 rowblocks of 1024 rows
  int ch = blockIdx.x & 63;  // 64 chunks
  int k0 = ch << 7;          // CPC codes per chunk
  const float* cb = cbn + (size_t)k0 * 8;  // wave-uniform base
  const float* hh = c2h + k0;
  int rbase = (rb << 10) + tid;  // rows rbase + j*256, j<4

#define DECL_ROW(j) float4 m##j##a, m##j##b; float b##j = 3.4e38f; int i##j = 0;
  DECL_ROW(0) DECL_ROW(1) DECL_ROW(2) DECL_ROW(3)
#undef DECL_ROW
#define LOAD_ROW(j) {                                                         \
    const float4* ep = (const float4*)(enc + (size_t)(rbase + (j << 8)) * 8); \
    m##j##a = ep[0]; m##j##b = ep[1]; }
  LOAD_ROW(0) LOAD_ROW(1) LOAD_ROW(2) LOAD_ROW(3)
#undef LOAD_ROW

#pragma unroll 4
  for (int k = 0; k < CPC; k++) {
    // wave-uniform, read-only, no aliasing writes -> s_load into SGPRs
    float c0 = cb[k * 8 + 0], c1 = cb[k * 8 + 1];
    float c2 = cb[k * 8 + 2], c3 = cb[k * 8 + 3];
    float c4 = cb[k * 8 + 4], c5 = cb[k * 8 + 5];
    float c6 = cb[k * 8 + 6], c7 = cb[k * 8 + 7];
    float cc = hh[k];
    int kk = k0 + k;
#define STEP(j) {                                                             \
    float s = cc;                                                             \
    s = fmaf(m##j##a.x, c0, s); s = fmaf(m##j##a.y, c1, s);                   \
    s = fmaf(m##j##a.z, c2, s); s = fmaf(m##j##a.w, c3, s);                   \
    s = fmaf(m##j##b.x, c4, s); s = fmaf(m##j##b.y, c5, s);                   \
    s = fmaf(m##j##b.z, c6, s); s = fmaf(m##j##b.w, c7, s);                   \
    if (s < b##j) { b##j = s; i##j = kk; } }
    STEP(0) STEP(1) STEP(2) STEP(3)
#undef STEP
  }
#define STORE_ROW(j) \
  part[(size_t)ch * 16384 + rbase + (j << 8)] = make_float2(b##j, __int_as_float(i##j));
  STORE_ROW(0) STORE_ROW(1) STORE_ROW(2) STORE_ROW(3)
#undef STORE_ROW
}

// ---------------- K2b: reduce chunk partials + gather codebook row -> WS_Q ----
__global__ __launch_bounds__(256) void k2b_reduce(
    const float* __restrict__ codebook, float* __restrict__ ws, float* __restrict__ out)
{
  int r = blockIdx.x * 256 + threadIdx.x;
  const float2* part = (const float2*)(ws + WS_PART);
  float best = 3.4e38f;
  int bi = 0;
#pragma unroll 8
  for (int ch = 0; ch < NCH; ch++) {
    float2 p = part[(size_t)ch * 16384 + r];
    if (p.x < best) { best = p.x; bi = __float_as_int(p.y); }  // ascending => first min
  }
  out[IDX_OFS + r] = (float)bi;
  ((int*)(ws + WS_IDXI))[r] = bi;
  const float4* cb = (const float4*)codebook;
  float4* q = (float4*)(ws + WS_Q + (size_t)r * 8);
  q[0] = cb[(size_t)bi * 2];
  q[1] = cb[(size_t)bi * 2 + 1];
}

// ---------------- K3: out = w_out @ q + b_out (HBM write-bound, no gathers) ----
__global__ __launch_bounds__(256) void k3_proj_out(
    const float* __restrict__ w_out, const float* __restrict__ b_out,
    const float* __restrict__ ws, float* __restrict__ out)
{
  int bx = blockIdx.x;
  int b = bx >> 7;
  int th = (bx >> 6) & 1;
  int dt = bx & 63;
  int tid = threadIdx.x;
  int t = (th << 10) + (tid << 2);
  const float4* qp = (const float4*)(ws + WS_Q + ((size_t)b * TTT + t) * 8);
  float4 c00 = qp[0], c01 = qp[1];
  float4 c10 = qp[2], c11 = qp[3];
  float4 c20 = qp[4], c21 = qp[5];
  float4 c30 = qp[6], c31 = qp[7];
  int d0 = dt << 4;
#pragma unroll 4
  for (int dd = 0; dd < 16; dd++) {
    int d = d0 + dd;
    const float* wr = w_out + (size_t)d * 8;
    float w0 = wr[0], w1 = wr[1], w2 = wr[2], w3 = wr[3];
    float w4 = wr[4], w5 = wr[5], w6 = wr[6], w7 = wr[7];
    float bb = b_out[d];
#define DOT8(lo, hi)                                                          \
    fmaf(w7, hi.w, fmaf(w6, hi.z, fmaf(w5, hi.y, fmaf(w4, hi.x,              \
    fmaf(w3, lo.w, fmaf(w2, lo.z, fmaf(w1, lo.y, fmaf(w0, lo.x, bb))))))))
    float4 r;
    r.x = DOT8(c00, c01);
    r.y = DOT8(c10, c11);
    r.z = DOT8(c20, c21);
    r.w = DOT8(c30, c31);
#undef DOT8
    *(float4*)(out + OUT_OFS + ((size_t)b * DIN + d) * TTT + t) = r;
  }
}

extern "C" void kernel_launch(void* const* d_in, const int* in_sizes, int n_in,
                              void* d_out, int out_size, void* d_ws, size_t ws_size,
                              hipStream_t stream) {
  const float* z        = (const float*)d_in[0];
  const float* w_in     = (const float*)d_in[1];
  const float* b_in     = (const float*)d_in[2];
  const float* w_out    = (const float*)d_in[3];
  const float* b_out    = (const float*)d_in[4];
  const float* codebook = (const float*)d_in[5];
  float* out = (float*)d_out;
  float* ws  = (float*)d_ws;

  k0_prep<<<dim3(37), dim3(256), 0, stream>>>(w_in, codebook, ws, out);
  k1_proj_in<<<dim3(512), dim3(256), 0, stream>>>(z, b_in, ws + WS_WT, ws + WS_ENC, out);
  k2_scan<<<dim3(1024), dim3(256), 0, stream>>>(ws + WS_CBN, ws + WS_C2, ws + WS_ENC,
                                                (float2*)(ws + WS_PART));
  k2b_reduce<<<dim3(64), dim3(256), 0, stream>>>(codebook, ws, out);
  k3_proj_out<<<dim3(1024), dim3(256), 0, stream>>>(w_out, b_out, ws, out);
}